// Round 15
// baseline (41.788 us; speedup 1.0000x reference)
//
#include <hip/hip_runtime.h>
#include <hip/hip_bf16.h>

#define N_   64
#define D_   128
#define L_   3136
#define K_   64
#define TL_  64
#define NG_  16     // pixel groups per image -> grid = 64*16 = 1024 blocks (2 rounds/CU, backfill)
// tiles per group: g==0 -> 4, else 3 (4 + 15*3 = 49 tiles of 64 pixels)
#define ASH  72     // As row stride in shorts (144B: 16B-aligned rows)
#define VSLAB ((size_t)N_ * K_ * D_)   // bf16 elements per V slab

typedef short  short8  __attribute__((ext_vector_type(8)));
typedef short  short4v __attribute__((ext_vector_type(4)));
typedef float  f32x16  __attribute__((ext_vector_type(16)));

static __device__ __forceinline__ float bf2f(short s) {
    return __uint_as_float(((unsigned)(unsigned short)s) << 16);
}
// packed RNE convert: lowers to v_cvt_pk_bf16_f32 (low16 = lo)
static __device__ __forceinline__ unsigned pk2(float lo, float hi) {
    __hip_bfloat162 b = __float22bfloat162_rn(make_float2(lo, hi));
    return *reinterpret_cast<unsigned*>(&b);
}

// Raw barrier: drains LDS (lgkmcnt) for write->barrier->read ordering, but
// does NOT drain vmcnt -- prefetch global loads stay in flight across it.
#define BARX() asm volatile("s_waitcnt lgkmcnt(0)\n\ts_barrier" ::: "memory")

// One tile, staged into LDS buffer (L1BUF/L2BUF alternate per tile parity).
// Barriers: A (staging RAW), B (dred RAW), C (As RAW). No D: next staging
// writes the OTHER buffer; this buffer is rewritten 2 tiles later, behind
// B(i), C(i), A(i+1).
#define PROCESS(TCUR, L1BUF, L2BUF)                                            \
    {                                                                          \
        const char* L1b = (const char*)(L1BUF);                                \
        const char* L2b = (const char*)(L2BUF);                                \
        /* sumsq partials (8 d each) -> wave shfl reduce (32 d) -> red4 */     \
        float s4[4];                                                           \
        _Pragma("unroll")                                                      \
        for (int j = 0; j < 4; ++j) {                                          \
            float s = 0.f;                                                     \
            _Pragma("unroll")                                                  \
            for (int r = 0; r < 8; ++r) {                                      \
                const float val = (&v[r].x)[j];                                \
                s = fmaf(val, val, s);                                         \
            }                                                                  \
            s4[j] = s;                                                         \
        }                                                                      \
        _Pragma("unroll")                                                      \
        for (int j = 0; j < 4; ++j) {                                          \
            s4[j] += __shfl_xor(s4[j], 16);                                    \
            s4[j] += __shfl_xor(s4[j], 32);                                    \
        }                                                                      \
        if (lane < 16)                                                         \
            *(float4*)&red4[wv][lane * 4] = make_float4(s4[0], s4[1], s4[2], s4[3]); \
        /* packed bf16 -> L1 + L2 (current parity buffer) */                   \
        _Pragma("unroll")                                                      \
        for (int j = 0; j < 4; ++j) {                                          \
            const int l = l0 + j;                                              \
            union { unsigned u[4]; short8 s; } f;                              \
            f.u[0] = pk2((&v[0].x)[j], (&v[1].x)[j]);                          \
            f.u[1] = pk2((&v[2].x)[j], (&v[3].x)[j]);                          \
            f.u[2] = pk2((&v[4].x)[j], (&v[5].x)[j]);                          \
            f.u[3] = pk2((&v[6].x)[j], (&v[7].x)[j]);                          \
            *(short8*)((char*)L1b + l * 256 + ((16 * q) ^ ((l & 15) << 4))) = f.s; \
        }                                                                      \
        _Pragma("unroll")                                                      \
        for (int r = 0; r < 8; ++r) {                                          \
            const int d = 8 * q + r;                                           \
            union { unsigned u[2]; short4v s; } f;                             \
            f.u[0] = pk2(v[r].x, v[r].y);                                      \
            f.u[1] = pk2(v[r].z, v[r].w);                                      \
            *(short4v*)((char*)L2b + d * 128 + ((l0 * 2) ^ ((d & 7) << 4))) = f.s; \
        }                                                                      \
        /* issue next tile's loads (v dead); stay in flight across barriers */ \
        if ((TCUR) + 1 < ntile) {                                              \
            const int p0n = (tile0 + (TCUR) + 1) * TL_;                        \
            _Pragma("unroll")                                                  \
            for (int r = 0; r < 8; ++r)                                        \
                v[r] = *(const float4*)(xb + (size_t)(8 * q + r) * L_ + p0n + l0); \
        }                                                                      \
        BARX();  /* A: tile staged (red4/L1/L2 visible) */                     \
        if (t < TL_) {                                                         \
            const float ss = red4[0][t] + red4[1][t] + red4[2][t] + red4[3][t]; \
            nrm_lds[t] = fmaxf(sqrtf(ss), 1e-12f);                             \
        }                                                                      \
        /* phase 1: R = W * X (quadrant Mt x Nt), contraction dk=128 */        \
        f32x16 r1 = {0};                                                       \
        {                                                                      \
            const int l = 32 * (wv >> 1) + lm;                                 \
            const int rowoff = l * 256;                                        \
            const int swz = (l & 15) << 4;                                     \
            __builtin_amdgcn_s_setprio(1);                                     \
            _Pragma("unroll")                                                  \
            for (int ks = 0; ks < 8; ++ks) {                                   \
                const short8 bfr = *(short8*)((char*)L1b + rowoff + (((16 * ks + 8 * lg) * 2) ^ swz)); \
                r1 = __builtin_amdgcn_mfma_f32_32x32x16_bf16(wf[ks], bfr, r1, 0, 0, 0); \
            }                                                                  \
            __builtin_amdgcn_s_setprio(0);                                     \
        }                                                                      \
        const int myl = 32 * (wv >> 1) + lm;                                   \
        const float ss16 = red4[0][myl] + red4[1][myl] + red4[2][myl] + red4[3][myl]; \
        const float invp = 1.f / fmaxf(sqrtf(ss16), 1e-12f);                   \
        /* softmax over k (no max-sub; |logit*inv| <= ||w_k|| ~ 0.6) */        \
        float e[16];                                                           \
        float s = 0.f;                                                         \
        _Pragma("unroll")                                                      \
        for (int r = 0; r < 16; ++r) { e[r] = __expf(r1[r] * invp); s += e[r]; } \
        s += __shfl_xor(s, 32);                                                \
        if (lane < 32) dred[wv][lm] = s;                                       \
        BARX();  /* B: dred ready (red4 consumed) */                           \
        const float denom = dred[wv][lm] + dred[wv ^ 1][lm];                   \
        const float sc = invp / denom;                                         \
        {                                                                      \
            const int colp = 32 * (wv >> 1) + lm;                              \
            _Pragma("unroll")                                                  \
            for (int rr = 0; rr < 8; ++rr) {                                   \
                const int r = 2 * rr;                                          \
                const int k = 32 * Mt + (r & 3) + 8 * (r >> 2) + 4 * lg;       \
                const unsigned u = pk2(e[r] * sc, e[r + 1] * sc);              \
                AsS[k * ASH + colp]       = (short)u;                          \
                AsS[(k + 1) * ASH + colp] = (short)(u >> 16);                  \
            }                                                                  \
        }                                                                      \
        BARX();  /* C: A_s ready */                                            \
        /* phase 2: V += A_s * X^T, contraction l=64 */                        \
        {                                                                      \
            short8 af[4];                                                      \
            const char* arow = AsRaw + (size_t)(32 * Mt + lm) * (ASH * 2);     \
            _Pragma("unroll")                                                  \
            for (int ks = 0; ks < 4; ++ks)                                     \
                af[ks] = *(const short8*)(arow + (16 * ks + 8 * lg) * 2);      \
            __builtin_amdgcn_s_setprio(1);                                     \
            _Pragma("unroll")                                                  \
            for (int nt = 0; nt < 2; ++nt) {                                   \
                const int dk = 32 * (2 * (wv >> 1) + nt) + lm;                 \
                const int rowoff = dk * 128;                                   \
                const int swz = (dk & 7) << 4;                                 \
                f32x16 a = (nt == 0) ? acc0 : acc1;                            \
                _Pragma("unroll")                                              \
                for (int ks = 0; ks < 4; ++ks) {                               \
                    const short8 bfr = *(short8*)((char*)L2b + rowoff + (((16 * ks + 8 * lg) * 2) ^ swz)); \
                    a = __builtin_amdgcn_mfma_f32_32x32x16_bf16(af[ks], bfr, a, 0, 0, 0); \
                }                                                              \
                if (nt == 0) acc0 = a; else acc1 = a;                          \
            }                                                                  \
            __builtin_amdgcn_s_setprio(0);                                     \
        }                                                                      \
        /* asum partial: asum[k] += sum_l A_s[k][l]*nrm[l] (vector reads) */   \
        {                                                                      \
            const int k  = 16 * wv + (lane & 15);                              \
            const int c4 = lane >> 4;                                          \
            const char* ap = AsRaw + (size_t)k * (ASH * 2) + c4 * 32;          \
            const short8 a0 = *(const short8*)ap;                              \
            const short8 a1 = *(const short8*)(ap + 16);                       \
            const float4* np = (const float4*)&nrm_lds[16 * c4];               \
            const float4 n0 = np[0], n1 = np[1], n2 = np[2], n3 = np[3];       \
            float ps = 0.f;                                                    \
            ps = fmaf(bf2f(a0[0]), n0.x, ps); ps = fmaf(bf2f(a0[1]), n0.y, ps); \
            ps = fmaf(bf2f(a0[2]), n0.z, ps); ps = fmaf(bf2f(a0[3]), n0.w, ps); \
            ps = fmaf(bf2f(a0[4]), n1.x, ps); ps = fmaf(bf2f(a0[5]), n1.y, ps); \
            ps = fmaf(bf2f(a0[6]), n1.z, ps); ps = fmaf(bf2f(a0[7]), n1.w, ps); \
            ps = fmaf(bf2f(a1[0]), n2.x, ps); ps = fmaf(bf2f(a1[1]), n2.y, ps); \
            ps = fmaf(bf2f(a1[2]), n2.z, ps); ps = fmaf(bf2f(a1[3]), n2.w, ps); \
            ps = fmaf(bf2f(a1[4]), n3.x, ps); ps = fmaf(bf2f(a1[5]), n3.y, ps); \
            ps = fmaf(bf2f(a1[6]), n3.z, ps); ps = fmaf(bf2f(a1[7]), n3.w, ps); \
            ps += __shfl_xor(ps, 16);                                          \
            ps += __shfl_xor(ps, 32);                                          \
            asum_acc += ps;                                                    \
        }                                                                      \
        /* no barrier D: next staging writes the other LDS buffer */           \
    }

// Full-MFMA fused NetVLAD main (r14 structure; NG=16 for backfill smoothing:
// 1024 blocks of 3-4 tiles, 2 scheduling rounds -- kills the synchronized
// 7-tile straggler tail of the 512-block/zero-backfill grid).
__global__ __launch_bounds__(256, 2)
void vlad_main(const float* __restrict__ x, const float* __restrict__ w,
               short* __restrict__ vout, float* __restrict__ aout)
{
    __shared__ __align__(16) short L1[2][TL_ * D_];  // [l][dk] bf16, swz ^((l&15)<<4), 2x16KB
    __shared__ __align__(16) short L2[2][D_ * TL_];  // [dk][l] bf16, swz ^((dk&7)<<4), 2x16KB
    __shared__ __align__(16) char  AsRaw[K_ * ASH * 2];  // bf16 a*inv [k][p], 9.2KB
    __shared__ __align__(16) float red4[4][TL_];     // per-wave 32-d sumsq partials, 1KB
    __shared__ __align__(16) float nrm_lds[TL_];
    __shared__ float dred[4][32];                    // softmax denominator exchange

    const int t    = threadIdx.x;
    const int lane = t & 63;
    const int wv   = __builtin_amdgcn_readfirstlane(t >> 6);  // 0..3
    const int n    = blockIdx.x / NG_;
    const int g    = blockIdx.x % NG_;
    const int tile0 = (g == 0) ? 0 : (3 * g + 1);
    const int ntile = (g == 0) ? 4 : 3;

    const int Mt = wv & 1;     // cluster-half (M) for both phases
    const int lg = lane >> 5;  // k-element group (0/1)
    const int lm = lane & 31;

    short* AsS = (short*)AsRaw;

    // ---- W fragments, loop-invariant, kept in 32 VGPRs ----
    short8 wf[8];
#pragma unroll
    for (int ks = 0; ks < 8; ++ks) {
        const float* wp = w + (size_t)(32 * Mt + lm) * D_ + 16 * ks + 8 * lg;
        const float4 wa = *(const float4*)wp;
        const float4 wb = *(const float4*)(wp + 4);
        union { unsigned u[4]; short8 s; } f;
        f.u[0] = pk2(wa.x, wa.y); f.u[1] = pk2(wa.z, wa.w);
        f.u[2] = pk2(wb.x, wb.y); f.u[3] = pk2(wb.z, wb.w);
        wf[ks] = f.s;
    }

    f32x16 acc0 = {0};   // V[k][d] C-frag, d-tile 2*(wv>>1)
    f32x16 acc1 = {0};   // d-tile 2*(wv>>1)+1
    float asum_acc = 0.f;

    const int q  = t >> 4;          // staging: d-rows 8q..8q+7
    const int l0 = (t & 15) * 4;    // staging: 4 pixels
    const float* xb = x + (size_t)n * D_ * L_;

    // ---- prologue: load tile 0 into registers ----
    float4 v[8];
    {
        const int p0 = tile0 * TL_;
#pragma unroll
        for (int r = 0; r < 8; ++r)
            v[r] = *(const float4*)(xb + (size_t)(8 * q + r) * L_ + p0 + l0);
    }

    for (int tp = 0; tp < ntile; tp += 2) {
        PROCESS(tp, L1[0], L2[0])
        if (tp + 1 < ntile) {
            PROCESS(tp + 1, L1[1], L2[1])
        }
    }

    // ---- commit: per-group bf16 slab (plain stores) ----
    {
        const int dbase0 = 32 * (2 * (wv >> 1));
        short* vb2 = vout + (size_t)g * VSLAB;
#pragma unroll
        for (int r = 0; r < 16; ++r) {
            const int k = 32 * Mt + (r & 3) + 8 * (r >> 2) + 4 * lg;
            short* row = vb2 + ((size_t)n * K_ + k) * D_ + lm;
            const unsigned u = pk2(acc0[r], acc1[r]);
            row[dbase0]      = (short)u;
            row[dbase0 + 32] = (short)(u >> 16);
        }
        if (lane < 16) {
            const int k = 16 * wv + lane;
            aout[(size_t)g * (N_ * K_) + n * K_ + k] = asum_acc;
        }
    }
}

// Finalize, spread: one block per (n, k-octet). Sum bf16 slabs, subtract a*c,
// intra-normalize over d. Global norm = sqrt(K) = 8 exactly (unit rows).
__global__ __launch_bounds__(256)
void vlad_fin(const short* __restrict__ vacc, const float* __restrict__ asum,
              const float* __restrict__ cent, float* __restrict__ out)
{
    const int t   = threadIdx.x;
    const int b   = blockIdx.x;
    const int n   = b >> 3;
    const int oct = b & 7;
    const int k   = oct * 8 + (t >> 5);   // 8 k-rows per block
    const int c   = t & 31;               // float4 column; d = 4c

    float a = 0.f;
#pragma unroll
    for (int g = 0; g < NG_; ++g) a += asum[(size_t)g * (N_ * K_) + n * K_ + k];

    const size_t roff = ((size_t)(n * K_ + k)) * D_ + c * 4;
    float4 v = make_float4(0.f, 0.f, 0.f, 0.f);
#pragma unroll
    for (int g = 0; g < NG_; ++g) {
        const short4v s = *(const short4v*)(vacc + (size_t)g * VSLAB + roff);
        v.x += bf2f(s[0]); v.y += bf2f(s[1]);
        v.z += bf2f(s[2]); v.w += bf2f(s[3]);
    }
    const float4 cc = ((const float4*)cent)[((size_t)k * D_ >> 2) + c];
    v.x -= a * cc.x; v.y -= a * cc.y; v.z -= a * cc.z; v.w -= a * cc.w;
    float ss = v.x * v.x + v.y * v.y + v.z * v.z + v.w * v.w;
    ss += __shfl_xor(ss, 1);
    ss += __shfl_xor(ss, 2);
    ss += __shfl_xor(ss, 4);
    ss += __shfl_xor(ss, 8);
    ss += __shfl_xor(ss, 16);             // stays within the 32-lane row group
    const float s1 = 0.125f / fmaxf(sqrtf(ss), 1e-12f);   // intra-norm * 1/sqrt(K)
    float4 o;
    o.x = v.x * s1; o.y = v.y * s1; o.z = v.z * s1; o.w = v.w * s1;
    *(float4*)(out + roff) = o;
}

extern "C" void kernel_launch(void* const* d_in, const int* in_sizes, int n_in,
                              void* d_out, int out_size, void* d_ws, size_t ws_size,
                              hipStream_t stream)
{
    const float* x = (const float*)d_in[0];   // [N, D, H, W]
    const float* w = (const float*)d_in[1];   // [K, D]
    const float* c = (const float*)d_in[2];   // [K, D]
    float* out = (float*)d_out;               // [N, K*D]

    short* vacc = (short*)d_ws;                          // NG bf16 V slabs (16.8MB)
    float* ap   = (float*)(vacc + NG_ * VSLAB);          // NG f32 asum slabs (262KB)

    vlad_main<<<dim3(N_ * NG_), dim3(256), 0, stream>>>(x, w, vacc, ap);
    vlad_fin<<<dim3(N_ * 8), dim3(256), 0, stream>>>(vacc, ap, c, out);
}

// Round 16
// 39.129 us; speedup vs baseline: 1.0679x; 1.0679x over previous
//
#include <hip/hip_runtime.h>
#include <hip/hip_bf16.h>

#define N_   64
#define D_   128
#define L_   3136
#define K_   64
#define TL_  64
#define NG_  8      // pixel groups per image -> grid = 64*8 = 512 = 2 blocks/CU (r15: more/shorter blocks regress)
// tiles per group: g==0 -> 7, else 6 (7 + 7*6 = 49 tiles of 64 pixels)
#define ASH  72     // As row stride in shorts (144B: 16B-aligned rows)
#define VSLAB ((size_t)N_ * K_ * D_)   // bf16 elements per V slab

typedef short  short8  __attribute__((ext_vector_type(8)));
typedef short  short4v __attribute__((ext_vector_type(4)));
typedef float  f32x16  __attribute__((ext_vector_type(16)));

static __device__ __forceinline__ float bf2f(short s) {
    return __uint_as_float(((unsigned)(unsigned short)s) << 16);
}
// packed RNE convert: lowers to v_cvt_pk_bf16_f32 (low16 = lo)
static __device__ __forceinline__ unsigned pk2(float lo, float hi) {
    __hip_bfloat162 b = __float22bfloat162_rn(make_float2(lo, hi));
    return *reinterpret_cast<unsigned*>(&b);
}

// Raw barrier: drains LDS (lgkmcnt) for write->barrier->read ordering, but
// does NOT drain vmcnt -- prefetch global loads stay in flight across it.
#define BARX() asm volatile("s_waitcnt lgkmcnt(0)\n\ts_barrier" ::: "memory")

// One tile. Barriers: A (staging RAW), C (As RAW) -- barrier B is GONE:
// phase 1 computes ALL 64 k per wave (wfA/wfB, shared B-frags), so the
// softmax denominator is wave-local (shfl_xor 32), no dred exchange.
// The Mt-duplicate waves split the As writes (Mt=0 -> k<32, Mt=1 -> k>=32).
// WAR safety: L1/L2 double-buffered (rewritten 2 tiles later, behind C(i),
// A(i+1)); red4 reads all precede C(i), next write after C(i); nrm_lds/As
// reads precede A(i+1), next writes after A(i+1).
#define PROCESS(TCUR, L1BUF, L2BUF)                                            \
    {                                                                          \
        const char* L1b = (const char*)(L1BUF);                                \
        const char* L2b = (const char*)(L2BUF);                                \
        /* sumsq partials (8 d each) -> wave shfl reduce (32 d) -> red4 */     \
        float s4[4];                                                           \
        _Pragma("unroll")                                                      \
        for (int j = 0; j < 4; ++j) {                                          \
            float s = 0.f;                                                     \
            _Pragma("unroll")                                                  \
            for (int r = 0; r < 8; ++r) {                                      \
                const float val = (&v[r].x)[j];                                \
                s = fmaf(val, val, s);                                         \
            }                                                                  \
            s4[j] = s;                                                         \
        }                                                                      \
        _Pragma("unroll")                                                      \
        for (int j = 0; j < 4; ++j) {                                          \
            s4[j] += __shfl_xor(s4[j], 16);                                    \
            s4[j] += __shfl_xor(s4[j], 32);                                    \
        }                                                                      \
        if (lane < 16)                                                         \
            *(float4*)&red4[wv][lane * 4] = make_float4(s4[0], s4[1], s4[2], s4[3]); \
        /* packed bf16 -> L1 + L2 (current parity buffer) */                   \
        _Pragma("unroll")                                                      \
        for (int j = 0; j < 4; ++j) {                                          \
            const int l = l0 + j;                                              \
            union { unsigned u[4]; short8 s; } f;                              \
            f.u[0] = pk2((&v[0].x)[j], (&v[1].x)[j]);                          \
            f.u[1] = pk2((&v[2].x)[j], (&v[3].x)[j]);                          \
            f.u[2] = pk2((&v[4].x)[j], (&v[5].x)[j]);                          \
            f.u[3] = pk2((&v[6].x)[j], (&v[7].x)[j]);                          \
            *(short8*)((char*)L1b + l * 256 + ((16 * q) ^ ((l & 15) << 4))) = f.s; \
        }                                                                      \
        _Pragma("unroll")                                                      \
        for (int r = 0; r < 8; ++r) {                                          \
            const int d = 8 * q + r;                                           \
            union { unsigned u[2]; short4v s; } f;                             \
            f.u[0] = pk2(v[r].x, v[r].y);                                      \
            f.u[1] = pk2(v[r].z, v[r].w);                                      \
            *(short4v*)((char*)L2b + d * 128 + ((l0 * 2) ^ ((d & 7) << 4))) = f.s; \
        }                                                                      \
        /* issue next tile's loads (v dead); stay in flight across barriers */ \
        if ((TCUR) + 1 < ntile) {                                              \
            const int p0n = (tile0 + (TCUR) + 1) * TL_;                        \
            _Pragma("unroll")                                                  \
            for (int r = 0; r < 8; ++r)                                        \
                v[r] = *(const float4*)(xb + (size_t)(8 * q + r) * L_ + p0n + l0); \
        }                                                                      \
        BARX();  /* A: tile staged (red4/L1/L2 visible) */                     \
        if (t < TL_) {                                                         \
            const float ss = red4[0][t] + red4[1][t] + red4[2][t] + red4[3][t]; \
            nrm_lds[t] = fmaxf(sqrtf(ss), 1e-12f);                             \
        }                                                                      \
        /* phase 1: FULL-K logits (all 64 k x 32 pixels per wave) */           \
        f32x16 r1a = {0}, r1b = {0};                                           \
        {                                                                      \
            const int l = 32 * (wv >> 1) + lm;                                 \
            const int rowoff = l * 256;                                        \
            const int swz = (l & 15) << 4;                                     \
            __builtin_amdgcn_s_setprio(1);                                     \
            _Pragma("unroll")                                                  \
            for (int ks = 0; ks < 8; ++ks) {                                   \
                const short8 bfr = *(short8*)((char*)L1b + rowoff + (((16 * ks + 8 * lg) * 2) ^ swz)); \
                r1a = __builtin_amdgcn_mfma_f32_32x32x16_bf16(wfA[ks], bfr, r1a, 0, 0, 0); \
                r1b = __builtin_amdgcn_mfma_f32_32x32x16_bf16(wfB[ks], bfr, r1b, 0, 0, 0); \
            }                                                                  \
            __builtin_amdgcn_s_setprio(0);                                     \
        }                                                                      \
        const int myl = 32 * (wv >> 1) + lm;                                   \
        const float ss16 = red4[0][myl] + red4[1][myl] + red4[2][myl] + red4[3][myl]; \
        const float invp = 1.f / fmaxf(sqrtf(ss16), 1e-12f);                   \
        /* softmax over k, wave-local (no max-sub; |logit*inv| <= ~0.6) */     \
        float e0[16], e1[16];                                                  \
        float s = 0.f;                                                         \
        _Pragma("unroll")                                                      \
        for (int r = 0; r < 16; ++r) { e0[r] = __expf(r1a[r] * invp); s += e0[r]; } \
        _Pragma("unroll")                                                      \
        for (int r = 0; r < 16; ++r) { e1[r] = __expf(r1b[r] * invp); s += e1[r]; } \
        s += __shfl_xor(s, 32);              /* combine lg halves in-wave */   \
        const float sc = invp / s;           /* A_s = a * inv */               \
        {                                                                      \
            const int colp = 32 * (wv >> 1) + lm;                              \
            if (Mt == 0) {                                                     \
                _Pragma("unroll")                                              \
                for (int rr = 0; rr < 8; ++rr) {                               \
                    const int r = 2 * rr;                                      \
                    const int k = (r & 3) + 8 * (r >> 2) + 4 * lg;             \
                    const unsigned u = pk2(e0[r] * sc, e0[r + 1] * sc);        \
                    AsS[k * ASH + colp]       = (short)u;                      \
                    AsS[(k + 1) * ASH + colp] = (short)(u >> 16);              \
                }                                                              \
            } else {                                                           \
                _Pragma("unroll")                                              \
                for (int rr = 0; rr < 8; ++rr) {                               \
                    const int r = 2 * rr;                                      \
                    const int k = 32 + (r & 3) + 8 * (r >> 2) + 4 * lg;        \
                    const unsigned u = pk2(e1[r] * sc, e1[r + 1] * sc);        \
                    AsS[k * ASH + colp]       = (short)u;                      \
                    AsS[(k + 1) * ASH + colp] = (short)(u >> 16);              \
                }                                                              \
            }                                                                  \
        }                                                                      \
        BARX();  /* C: A_s ready */                                            \
        /* phase 2: V += A_s * X^T, contraction l=64 */                        \
        {                                                                      \
            short8 af[4];                                                      \
            const char* arow = AsRaw + (size_t)(32 * Mt + lm) * (ASH * 2);     \
            _Pragma("unroll")                                                  \
            for (int ks = 0; ks < 4; ++ks)                                     \
                af[ks] = *(const short8*)(arow + (16 * ks + 8 * lg) * 2);      \
            __builtin_amdgcn_s_setprio(1);                                     \
            _Pragma("unroll")                                                  \
            for (int nt = 0; nt < 2; ++nt) {                                   \
                const int dk = 32 * (2 * (wv >> 1) + nt) + lm;                 \
                const int rowoff = dk * 128;                                   \
                const int swz = (dk & 7) << 4;                                 \
                f32x16 a = (nt == 0) ? acc0 : acc1;                            \
                _Pragma("unroll")                                              \
                for (int ks = 0; ks < 4; ++ks) {                               \
                    const short8 bfr = *(short8*)((char*)L2b + rowoff + (((16 * ks + 8 * lg) * 2) ^ swz)); \
                    a = __builtin_amdgcn_mfma_f32_32x32x16_bf16(af[ks], bfr, a, 0, 0, 0); \
                }                                                              \
                if (nt == 0) acc0 = a; else acc1 = a;                          \
            }                                                                  \
            __builtin_amdgcn_s_setprio(0);                                     \
        }                                                                      \
        /* asum partial: asum[k] += sum_l A_s[k][l]*nrm[l] (vector reads) */   \
        {                                                                      \
            const int k  = 16 * wv + (lane & 15);                              \
            const int c4 = lane >> 4;                                          \
            const char* ap = AsRaw + (size_t)k * (ASH * 2) + c4 * 32;          \
            const short8 a0 = *(const short8*)ap;                              \
            const short8 a1 = *(const short8*)(ap + 16);                       \
            const float4* np = (const float4*)&nrm_lds[16 * c4];               \
            const float4 n0 = np[0], n1 = np[1], n2 = np[2], n3 = np[3];       \
            float ps = 0.f;                                                    \
            ps = fmaf(bf2f(a0[0]), n0.x, ps); ps = fmaf(bf2f(a0[1]), n0.y, ps); \
            ps = fmaf(bf2f(a0[2]), n0.z, ps); ps = fmaf(bf2f(a0[3]), n0.w, ps); \
            ps = fmaf(bf2f(a0[4]), n1.x, ps); ps = fmaf(bf2f(a0[5]), n1.y, ps); \
            ps = fmaf(bf2f(a0[6]), n1.z, ps); ps = fmaf(bf2f(a0[7]), n1.w, ps); \
            ps = fmaf(bf2f(a1[0]), n2.x, ps); ps = fmaf(bf2f(a1[1]), n2.y, ps); \
            ps = fmaf(bf2f(a1[2]), n2.z, ps); ps = fmaf(bf2f(a1[3]), n2.w, ps); \
            ps = fmaf(bf2f(a1[4]), n3.x, ps); ps = fmaf(bf2f(a1[5]), n3.y, ps); \
            ps = fmaf(bf2f(a1[6]), n3.z, ps); ps = fmaf(bf2f(a1[7]), n3.w, ps); \
            ps += __shfl_xor(ps, 16);                                          \
            ps += __shfl_xor(ps, 32);                                          \
            asum_acc += ps;                                                    \
        }                                                                      \
        /* no barrier D: next staging writes the other LDS buffer */           \
    }

// Full-MFMA fused NetVLAD main (r14 base + full-K phase1, 2 barriers/tile).
__global__ __launch_bounds__(256, 2)
void vlad_main(const float* __restrict__ x, const float* __restrict__ w,
               short* __restrict__ vout, float* __restrict__ aout)
{
    __shared__ __align__(16) short L1[2][TL_ * D_];  // [l][dk] bf16, swz ^((l&15)<<4), 2x16KB
    __shared__ __align__(16) short L2[2][D_ * TL_];  // [dk][l] bf16, swz ^((dk&7)<<4), 2x16KB
    __shared__ __align__(16) char  AsRaw[K_ * ASH * 2];  // bf16 a*inv [k][p], 9.2KB
    __shared__ __align__(16) float red4[4][TL_];     // per-wave 32-d sumsq partials, 1KB
    __shared__ __align__(16) float nrm_lds[TL_];

    const int t    = threadIdx.x;
    const int lane = t & 63;
    const int wv   = __builtin_amdgcn_readfirstlane(t >> 6);  // 0..3
    const int n    = blockIdx.x / NG_;
    const int g    = blockIdx.x % NG_;
    const int tile0 = (g == 0) ? 0 : (7 + 6 * (g - 1));
    const int ntile = (g == 0) ? 7 : 6;

    const int Mt = wv & 1;     // As-write half / phase-2 M-quadrant
    const int lg = lane >> 5;  // k-element group (0/1)
    const int lm = lane & 31;

    short* AsS = (short*)AsRaw;

    // ---- W fragments for ALL 64 k, loop-invariant, 64 VGPRs ----
    short8 wfA[8], wfB[8];
#pragma unroll
    for (int ks = 0; ks < 8; ++ks) {
        const float* wpa = w + (size_t)lm * D_ + 16 * ks + 8 * lg;
        const float4 a0 = *(const float4*)wpa;
        const float4 a1 = *(const float4*)(wpa + 4);
        union { unsigned u[4]; short8 s; } fa;
        fa.u[0] = pk2(a0.x, a0.y); fa.u[1] = pk2(a0.z, a0.w);
        fa.u[2] = pk2(a1.x, a1.y); fa.u[3] = pk2(a1.z, a1.w);
        wfA[ks] = fa.s;
        const float* wpb = w + (size_t)(32 + lm) * D_ + 16 * ks + 8 * lg;
        const float4 b0 = *(const float4*)wpb;
        const float4 b1 = *(const float4*)(wpb + 4);
        union { unsigned u[4]; short8 s; } fb;
        fb.u[0] = pk2(b0.x, b0.y); fb.u[1] = pk2(b0.z, b0.w);
        fb.u[2] = pk2(b1.x, b1.y); fb.u[3] = pk2(b1.z, b1.w);
        wfB[ks] = fb.s;
    }

    f32x16 acc0 = {0};   // V[k][d] C-frag, d-tile 2*(wv>>1)
    f32x16 acc1 = {0};   // d-tile 2*(wv>>1)+1
    float asum_acc = 0.f;

    const int q  = t >> 4;          // staging: d-rows 8q..8q+7
    const int l0 = (t & 15) * 4;    // staging: 4 pixels
    const float* xb = x + (size_t)n * D_ * L_;

    // ---- prologue: load tile 0 into registers ----
    float4 v[8];
    {
        const int p0 = tile0 * TL_;
#pragma unroll
        for (int r = 0; r < 8; ++r)
            v[r] = *(const float4*)(xb + (size_t)(8 * q + r) * L_ + p0 + l0);
    }

    for (int tp = 0; tp < ntile; tp += 2) {
        PROCESS(tp, L1[0], L2[0])
        if (tp + 1 < ntile) {
            PROCESS(tp + 1, L1[1], L2[1])
        }
    }

    // ---- commit: per-group bf16 slab (plain stores) ----
    {
        const int dbase0 = 32 * (2 * (wv >> 1));
        short* vb2 = vout + (size_t)g * VSLAB;
#pragma unroll
        for (int r = 0; r < 16; ++r) {
            const int k = 32 * Mt + (r & 3) + 8 * (r >> 2) + 4 * lg;
            short* row = vb2 + ((size_t)n * K_ + k) * D_ + lm;
            const unsigned u = pk2(acc0[r], acc1[r]);
            row[dbase0]      = (short)u;
            row[dbase0 + 32] = (short)(u >> 16);
        }
        if (lane < 16) {
            const int k = 16 * wv + lane;
            aout[(size_t)g * (N_ * K_) + n * K_ + k] = asum_acc;
        }
    }
}

// Finalize, spread: one block per (n, k-octet). Sum bf16 slabs, subtract a*c,
// intra-normalize over d. Global norm = sqrt(K) = 8 exactly (unit rows).
__global__ __launch_bounds__(256)
void vlad_fin(const short* __restrict__ vacc, const float* __restrict__ asum,
              const float* __restrict__ cent, float* __restrict__ out)
{
    const int t   = threadIdx.x;
    const int b   = blockIdx.x;
    const int n   = b >> 3;
    const int oct = b & 7;
    const int k   = oct * 8 + (t >> 5);   // 8 k-rows per block
    const int c   = t & 31;               // float4 column; d = 4c

    float a = 0.f;
#pragma unroll
    for (int g = 0; g < NG_; ++g) a += asum[(size_t)g * (N_ * K_) + n * K_ + k];

    const size_t roff = ((size_t)(n * K_ + k)) * D_ + c * 4;
    float4 v = make_float4(0.f, 0.f, 0.f, 0.f);
#pragma unroll
    for (int g = 0; g < NG_; ++g) {
        const short4v s = *(const short4v*)(vacc + (size_t)g * VSLAB + roff);
        v.x += bf2f(s[0]); v.y += bf2f(s[1]);
        v.z += bf2f(s[2]); v.w += bf2f(s[3]);
    }
    const float4 cc = ((const float4*)cent)[((size_t)k * D_ >> 2) + c];
    v.x -= a * cc.x; v.y -= a * cc.y; v.z -= a * cc.z; v.w -= a * cc.w;
    float ss = v.x * v.x + v.y * v.y + v.z * v.z + v.w * v.w;
    ss += __shfl_xor(ss, 1);
    ss += __shfl_xor(ss, 2);
    ss += __shfl_xor(ss, 4);
    ss += __shfl_xor(ss, 8);
    ss += __shfl_xor(ss, 16);             // stays within the 32-lane row group
    const float s1 = 0.125f / fmaxf(sqrtf(ss), 1e-12f);   // intra-norm * 1/sqrt(K)
    float4 o;
    o.x = v.x * s1; o.y = v.y * s1; o.z = v.z * s1; o.w = v.w * s1;
    *(float4*)(out + roff) = o;
}

extern "C" void kernel_launch(void* const* d_in, const int* in_sizes, int n_in,
                              void* d_out, int out_size, void* d_ws, size_t ws_size,
                              hipStream_t stream)
{
    const float* x = (const float*)d_in[0];   // [N, D, H, W]
    const float* w = (const float*)d_in[1];   // [K, D]
    const float* c = (const float*)d_in[2];   // [K, D]
    float* out = (float*)d_out;               // [N, K*D]

    short* vacc = (short*)d_ws;                          // NG bf16 V slabs (8.4MB)
    float* ap   = (float*)(vacc + NG_ * VSLAB);          // NG f32 asum slabs (131KB)

    vlad_main<<<dim3(N_ * NG_), dim3(256), 0, stream>>>(x, w, vacc, ap);
    vlad_fin<<<dim3(N_ * 8), dim3(256), 0, stream>>>(vacc, ap, c, out);
}

// Round 17
// 34.499 us; speedup vs baseline: 1.2113x; 1.1342x over previous
//
#include <hip/hip_runtime.h>
#include <hip/hip_bf16.h>

#define N_   64
#define D_   128
#define L_   3136
#define K_   64
#define TL_  64
#define NG_  8      // pixel groups per image -> grid = 64*8 = 512 = 2 blocks/CU
// tiles per group: g==0 -> 7, else 6 (7 + 7*6 = 49 tiles of 64 pixels)
#define ASH  72     // As row stride in shorts (144B: 16B-aligned rows)
#define VSLAB ((size_t)N_ * K_ * D_)   // bf16 elements per V slab

typedef short  short8  __attribute__((ext_vector_type(8)));
typedef short  short4v __attribute__((ext_vector_type(4)));
typedef float  f32x16  __attribute__((ext_vector_type(16)));

static __device__ __forceinline__ float bf2f(short s) {
    return __uint_as_float(((unsigned)(unsigned short)s) << 16);
}
// packed RNE convert: lowers to v_cvt_pk_bf16_f32 (low16 = lo)
static __device__ __forceinline__ unsigned pk2(float lo, float hi) {
    __hip_bfloat162 b = __float22bfloat162_rn(make_float2(lo, hi));
    return *reinterpret_cast<unsigned*>(&b);
}

// Raw barrier: drains LDS (lgkmcnt) for write->barrier->read ordering, but
// does NOT drain vmcnt -- prefetch global loads stay in flight across it.
#define BARX() asm volatile("s_waitcnt lgkmcnt(0)\n\ts_barrier" ::: "memory")

// One tile, staged into LDS buffer (L1BUF/L2BUF alternate per tile parity).
// Barriers: A (staging RAW), B (dred RAW), C (As RAW). No D: next staging
// writes the OTHER buffer; this buffer is rewritten 2 tiles later, behind
// B(i), C(i), A(i+1).
// r17: staging consumes v[r] INCREMENTALLY (per-r L2 write + sumsq partial
// as each load lands -> fine-grained vmcnt), then the L1 writes that need
// all 8. r14 computed sumsq first, draining all 8 loads before any LDS write.
#define PROCESS(TCUR, L1BUF, L2BUF)                                            \
    {                                                                          \
        const char* L1b = (const char*)(L1BUF);                                \
        const char* L2b = (const char*)(L2BUF);                                \
        float s4[4];                                                           \
        _Pragma("unroll")                                                      \
        for (int j = 0; j < 4; ++j) s4[j] = 0.f;                               \
        /* per-r: L2 write + sumsq partials as v[r] arrives */                 \
        _Pragma("unroll")                                                      \
        for (int r = 0; r < 8; ++r) {                                          \
            const int d = 8 * q + r;                                           \
            union { unsigned u[2]; short4v s; } f;                             \
            f.u[0] = pk2(v[r].x, v[r].y);                                      \
            f.u[1] = pk2(v[r].z, v[r].w);                                      \
            *(short4v*)((char*)L2b + d * 128 + ((l0 * 2) ^ ((d & 7) << 4))) = f.s; \
            s4[0] = fmaf(v[r].x, v[r].x, s4[0]);                               \
            s4[1] = fmaf(v[r].y, v[r].y, s4[1]);                               \
            s4[2] = fmaf(v[r].z, v[r].z, s4[2]);                               \
            s4[3] = fmaf(v[r].w, v[r].w, s4[3]);                               \
        }                                                                      \
        /* L1 writes (need all 8 rows) */                                      \
        _Pragma("unroll")                                                      \
        for (int j = 0; j < 4; ++j) {                                          \
            const int l = l0 + j;                                              \
            union { unsigned u[4]; short8 s; } f;                              \
            f.u[0] = pk2((&v[0].x)[j], (&v[1].x)[j]);                          \
            f.u[1] = pk2((&v[2].x)[j], (&v[3].x)[j]);                          \
            f.u[2] = pk2((&v[4].x)[j], (&v[5].x)[j]);                          \
            f.u[3] = pk2((&v[6].x)[j], (&v[7].x)[j]);                          \
            *(short8*)((char*)L1b + l * 256 + ((16 * q) ^ ((l & 15) << 4))) = f.s; \
        }                                                                      \
        /* wave shfl reduce of sumsq partials -> red4 */                       \
        _Pragma("unroll")                                                      \
        for (int j = 0; j < 4; ++j) {                                          \
            s4[j] += __shfl_xor(s4[j], 16);                                    \
            s4[j] += __shfl_xor(s4[j], 32);                                    \
        }                                                                      \
        if (lane < 16)                                                         \
            *(float4*)&red4[wv][lane * 4] = make_float4(s4[0], s4[1], s4[2], s4[3]); \
        /* issue next tile's loads (v dead); stay in flight across barriers */ \
        if ((TCUR) + 1 < ntile) {                                              \
            const int p0n = (tile0 + (TCUR) + 1) * TL_;                        \
            _Pragma("unroll")                                                  \
            for (int r = 0; r < 8; ++r)                                        \
                v[r] = *(const float4*)(xb + (size_t)(8 * q + r) * L_ + p0n + l0); \
        }                                                                      \
        BARX();  /* A: tile staged (red4/L1/L2 visible) */                     \
        if (t < TL_) {                                                         \
            const float ss = red4[0][t] + red4[1][t] + red4[2][t] + red4[3][t]; \
            nrm_lds[t] = fmaxf(sqrtf(ss), 1e-12f);                             \
        }                                                                      \
        /* phase 1: R = W * X (quadrant Mt x Nt), contraction dk=128 */        \
        f32x16 r1 = {0};                                                       \
        {                                                                      \
            const int l = 32 * (wv >> 1) + lm;                                 \
            const int rowoff = l * 256;                                        \
            const int swz = (l & 15) << 4;                                     \
            __builtin_amdgcn_s_setprio(1);                                     \
            _Pragma("unroll")                                                  \
            for (int ks = 0; ks < 8; ++ks) {                                   \
                const short8 bfr = *(short8*)((char*)L1b + rowoff + (((16 * ks + 8 * lg) * 2) ^ swz)); \
                r1 = __builtin_amdgcn_mfma_f32_32x32x16_bf16(wf[ks], bfr, r1, 0, 0, 0); \
            }                                                                  \
            __builtin_amdgcn_s_setprio(0);                                     \
        }                                                                      \
        const int myl = 32 * (wv >> 1) + lm;                                   \
        const float ss16 = red4[0][myl] + red4[1][myl] + red4[2][myl] + red4[3][myl]; \
        const float invp = 1.f / fmaxf(sqrtf(ss16), 1e-12f);                   \
        /* softmax over k (no max-sub; |logit*inv| <= ||w_k|| ~ 0.6) */        \
        float e[16];                                                           \
        float s = 0.f;                                                         \
        _Pragma("unroll")                                                      \
        for (int r = 0; r < 16; ++r) { e[r] = __expf(r1[r] * invp); s += e[r]; } \
        s += __shfl_xor(s, 32);                                                \
        if (lane < 32) dred[wv][lm] = s;                                       \
        BARX();  /* B: dred ready (red4 consumed) */                           \
        const float denom = dred[wv][lm] + dred[wv ^ 1][lm];                   \
        const float sc = invp / denom;                                         \
        {                                                                      \
            const int colp = 32 * (wv >> 1) + lm;                              \
            _Pragma("unroll")                                                  \
            for (int rr = 0; rr < 8; ++rr) {                                   \
                const int r = 2 * rr;                                          \
                const int k = 32 * Mt + (r & 3) + 8 * (r >> 2) + 4 * lg;       \
                const unsigned u = pk2(e[r] * sc, e[r + 1] * sc);              \
                AsS[k * ASH + colp]       = (short)u;                          \
                AsS[(k + 1) * ASH + colp] = (short)(u >> 16);                  \
            }                                                                  \
        }                                                                      \
        BARX();  /* C: A_s ready */                                            \
        /* phase 2: V += A_s * X^T, contraction l=64 */                        \
        {                                                                      \
            short8 af[4];                                                      \
            const char* arow = AsRaw + (size_t)(32 * Mt + lm) * (ASH * 2);     \
            _Pragma("unroll")                                                  \
            for (int ks = 0; ks < 4; ++ks)                                     \
                af[ks] = *(const short8*)(arow + (16 * ks + 8 * lg) * 2);      \
            __builtin_amdgcn_s_setprio(1);                                     \
            _Pragma("unroll")                                                  \
            for (int nt = 0; nt < 2; ++nt) {                                   \
                const int dk = 32 * (2 * (wv >> 1) + nt) + lm;                 \
                const int rowoff = dk * 128;                                   \
                const int swz = (dk & 7) << 4;                                 \
                f32x16 a = (nt == 0) ? acc0 : acc1;                            \
                _Pragma("unroll")                                              \
                for (int ks = 0; ks < 4; ++ks) {                               \
                    const short8 bfr = *(short8*)((char*)L2b + rowoff + (((16 * ks + 8 * lg) * 2) ^ swz)); \
                    a = __builtin_amdgcn_mfma_f32_32x32x16_bf16(af[ks], bfr, a, 0, 0, 0); \
                }                                                              \
                if (nt == 0) acc0 = a; else acc1 = a;                          \
            }                                                                  \
            __builtin_amdgcn_s_setprio(0);                                     \
        }                                                                      \
        /* asum partial: asum[k] += sum_l A_s[k][l]*nrm[l] (vector reads) */   \
        {                                                                      \
            const int k  = 16 * wv + (lane & 15);                              \
            const int c4 = lane >> 4;                                          \
            const char* ap = AsRaw + (size_t)k * (ASH * 2) + c4 * 32;          \
            const short8 a0 = *(const short8*)ap;                              \
            const short8 a1 = *(const short8*)(ap + 16);                       \
            const float4* np = (const float4*)&nrm_lds[16 * c4];               \
            const float4 n0 = np[0], n1 = np[1], n2 = np[2], n3 = np[3];       \
            float ps = 0.f;                                                    \
            ps = fmaf(bf2f(a0[0]), n0.x, ps); ps = fmaf(bf2f(a0[1]), n0.y, ps); \
            ps = fmaf(bf2f(a0[2]), n0.z, ps); ps = fmaf(bf2f(a0[3]), n0.w, ps); \
            ps = fmaf(bf2f(a0[4]), n1.x, ps); ps = fmaf(bf2f(a0[5]), n1.y, ps); \
            ps = fmaf(bf2f(a0[6]), n1.z, ps); ps = fmaf(bf2f(a0[7]), n1.w, ps); \
            ps = fmaf(bf2f(a1[0]), n2.x, ps); ps = fmaf(bf2f(a1[1]), n2.y, ps); \
            ps = fmaf(bf2f(a1[2]), n2.z, ps); ps = fmaf(bf2f(a1[3]), n2.w, ps); \
            ps = fmaf(bf2f(a1[4]), n3.x, ps); ps = fmaf(bf2f(a1[5]), n3.y, ps); \
            ps = fmaf(bf2f(a1[6]), n3.z, ps); ps = fmaf(bf2f(a1[7]), n3.w, ps); \
            ps += __shfl_xor(ps, 16);                                          \
            ps += __shfl_xor(ps, 32);                                          \
            asum_acc += ps;                                                    \
        }                                                                      \
        /* no barrier D: next staging writes the other LDS buffer */           \
    }

// Full-MFMA fused NetVLAD main (r14 structure restored; r16's full-K phase1
// regressed -- +64 VGPR of W-frags cost more than barrier B's latency).
__global__ __launch_bounds__(256, 2)
void vlad_main(const float* __restrict__ x, const float* __restrict__ w,
               short* __restrict__ vout, float* __restrict__ aout)
{
    __shared__ __align__(16) short L1[2][TL_ * D_];  // [l][dk] bf16, swz ^((l&15)<<4), 2x16KB
    __shared__ __align__(16) short L2[2][D_ * TL_];  // [dk][l] bf16, swz ^((dk&7)<<4), 2x16KB
    __shared__ __align__(16) char  AsRaw[K_ * ASH * 2];  // bf16 a*inv [k][p], 9.2KB
    __shared__ __align__(16) float red4[4][TL_];     // per-wave 32-d sumsq partials, 1KB
    __shared__ __align__(16) float nrm_lds[TL_];
    __shared__ float dred[4][32];                    // softmax denominator exchange

    const int t    = threadIdx.x;
    const int lane = t & 63;
    const int wv   = __builtin_amdgcn_readfirstlane(t >> 6);  // 0..3
    const int n    = blockIdx.x / NG_;
    const int g    = blockIdx.x % NG_;
    const int tile0 = (g == 0) ? 0 : (7 + 6 * (g - 1));
    const int ntile = (g == 0) ? 7 : 6;

    const int Mt = wv & 1;     // cluster-half (M) for both phases
    const int lg = lane >> 5;  // k-element group (0/1)
    const int lm = lane & 31;

    short* AsS = (short*)AsRaw;

    // ---- W fragments, loop-invariant, kept in 32 VGPRs ----
    short8 wf[8];
#pragma unroll
    for (int ks = 0; ks < 8; ++ks) {
        const float* wp = w + (size_t)(32 * Mt + lm) * D_ + 16 * ks + 8 * lg;
        const float4 wa = *(const float4*)wp;
        const float4 wb = *(const float4*)(wp + 4);
        union { unsigned u[4]; short8 s; } f;
        f.u[0] = pk2(wa.x, wa.y); f.u[1] = pk2(wa.z, wa.w);
        f.u[2] = pk2(wb.x, wb.y); f.u[3] = pk2(wb.z, wb.w);
        wf[ks] = f.s;
    }

    f32x16 acc0 = {0};   // V[k][d] C-frag, d-tile 2*(wv>>1)
    f32x16 acc1 = {0};   // d-tile 2*(wv>>1)+1
    float asum_acc = 0.f;

    const int q  = t >> 4;          // staging: d-rows 8q..8q+7
    const int l0 = (t & 15) * 4;    // staging: 4 pixels
    const float* xb = x + (size_t)n * D_ * L_;

    // ---- prologue: load tile 0 into registers ----
    float4 v[8];
    {
        const int p0 = tile0 * TL_;
#pragma unroll
        for (int r = 0; r < 8; ++r)
            v[r] = *(const float4*)(xb + (size_t)(8 * q + r) * L_ + p0 + l0);
    }

    for (int tp = 0; tp < ntile; tp += 2) {
        PROCESS(tp, L1[0], L2[0])
        if (tp + 1 < ntile) {
            PROCESS(tp + 1, L1[1], L2[1])
        }
    }

    // ---- commit: per-group bf16 slab (plain stores) ----
    {
        const int dbase0 = 32 * (2 * (wv >> 1));
        short* vb2 = vout + (size_t)g * VSLAB;
#pragma unroll
        for (int r = 0; r < 16; ++r) {
            const int k = 32 * Mt + (r & 3) + 8 * (r >> 2) + 4 * lg;
            short* row = vb2 + ((size_t)n * K_ + k) * D_ + lm;
            const unsigned u = pk2(acc0[r], acc1[r]);
            row[dbase0]      = (short)u;
            row[dbase0 + 32] = (short)(u >> 16);
        }
        if (lane < 16) {
            const int k = 16 * wv + lane;
            aout[(size_t)g * (N_ * K_) + n * K_ + k] = asum_acc;
        }
    }
}

// Finalize, spread: one block per (n, k-octet). Sum bf16 slabs, subtract a*c,
// intra-normalize over d. Global norm = sqrt(K) = 8 exactly (unit rows).
__global__ __launch_bounds__(256)
void vlad_fin(const short* __restrict__ vacc, const float* __restrict__ asum,
              const float* __restrict__ cent, float* __restrict__ out)
{
    const int t   = threadIdx.x;
    const int b   = blockIdx.x;
    const int n   = b >> 3;
    const int oct = b & 7;
    const int k   = oct * 8 + (t >> 5);   // 8 k-rows per block
    const int c   = t & 31;               // float4 column; d = 4c

    float a = 0.f;
#pragma unroll
    for (int g = 0; g < NG_; ++g) a += asum[(size_t)g * (N_ * K_) + n * K_ + k];

    const size_t roff = ((size_t)(n * K_ + k)) * D_ + c * 4;
    float4 v = make_float4(0.f, 0.f, 0.f, 0.f);
#pragma unroll
    for (int g = 0; g < NG_; ++g) {
        const short4v s = *(const short4v*)(vacc + (size_t)g * VSLAB + roff);
        v.x += bf2f(s[0]); v.y += bf2f(s[1]);
        v.z += bf2f(s[2]); v.w += bf2f(s[3]);
    }
    const float4 cc = ((const float4*)cent)[((size_t)k * D_ >> 2) + c];
    v.x -= a * cc.x; v.y -= a * cc.y; v.z -= a * cc.z; v.w -= a * cc.w;
    float ss = v.x * v.x + v.y * v.y + v.z * v.z + v.w * v.w;
    ss += __shfl_xor(ss, 1);
    ss += __shfl_xor(ss, 2);
    ss += __shfl_xor(ss, 4);
    ss += __shfl_xor(ss, 8);
    ss += __shfl_xor(ss, 16);             // stays within the 32-lane row group
    const float s1 = 0.125f / fmaxf(sqrtf(ss), 1e-12f);   // intra-norm * 1/sqrt(K)
    float4 o;
    o.x = v.x * s1; o.y = v.y * s1; o.z = v.z * s1; o.w = v.w * s1;
    *(float4*)(out + roff) = o;
}

extern "C" void kernel_launch(void* const* d_in, const int* in_sizes, int n_in,
                              void* d_out, int out_size, void* d_ws, size_t ws_size,
                              hipStream_t stream)
{
    const float* x = (const float*)d_in[0];   // [N, D, H, W]
    const float* w = (const float*)d_in[1];   // [K, D]
    const float* c = (const float*)d_in[2];   // [K, D]
    float* out = (float*)d_out;               // [N, K*D]

    short* vacc = (short*)d_ws;                          // NG bf16 V slabs (8.4MB)
    float* ap   = (float*)(vacc + NG_ * VSLAB);          // NG f32 asum slabs (131KB)

    vlad_main<<<dim3(N_ * NG_), dim3(256), 0, stream>>>(x, w, vacc, ap);
    vlad_fin<<<dim3(N_ * 8), dim3(256), 0, stream>>>(vacc, ap, c, out);
}